// Round 2
// 549.462 us; speedup vs baseline: 1.0403x; 1.0403x over previous
//
#include <hip/hip_runtime.h>
#include <math.h>

// Problem constants (match reference)
constexpr int Bn = 4, Rn = 16384, Sn = 48, Cn = 32;
constexpr int NRAY = Bn * Rn;                 // 65536 rays
constexpr int SM1  = Sn - 1;                  // 47 segments
constexpr int OUT_DEPTH_OFF = NRAY * Cn;      // rgb block size
constexpr int OUT_W_OFF     = OUT_DEPTH_OFF + NRAY;

// LDS row strides (floats). VSTR=52: 16B-aligned rows (52*4=208, 208%16==0).
// WSTR=49 for the weights staging (breaks power-of-2 bank stride).
constexpr int VSTR = 52;
constexpr int WSTR = 49;

// ---- pass 0: init global min/max cells in workspace --------------------
__global__ void k_init(unsigned int* ws) {
  ws[0] = 0xFFFFFFFFu;  // running min (uint order == float order for positives)
  ws[1] = 0u;           // running max
}

// ---- pass 1: global min/max of depths (sorted per ray -> first/last) ---
__global__ void k_minmax(const float* __restrict__ depths, unsigned int* ws) {
  int ray = blockIdx.x * blockDim.x + threadIdx.x;
  float lo = depths[(size_t)ray * Sn];
  float hi = depths[(size_t)ray * Sn + (Sn - 1)];
#pragma unroll
  for (int off = 32; off > 0; off >>= 1) {
    lo = fminf(lo, __shfl_down(lo, off, 64));
    hi = fmaxf(hi, __shfl_down(hi, off, 64));
  }
  __shared__ float slo[4], shi[4];
  int wv = threadIdx.x >> 6;
  if ((threadIdx.x & 63) == 0) { slo[wv] = lo; shi[wv] = hi; }
  __syncthreads();
  if (threadIdx.x == 0) {
    for (int i = 1; i < 4; ++i) { lo = fminf(lo, slo[i]); hi = fmaxf(hi, shi[i]); }
    atomicMin(ws + 0, __float_as_uint(lo));
    atomicMax(ws + 1, __float_as_uint(hi));
  }
}

// ---- pass 2: scan-then-stream ray march --------------------------------
// 8 lanes per ray. Phase 1: parallel alpha + 8-lane product scan over
// dens/deps (25 MB) -> weights w_s, v_t = 0.5*(w_{t-1}+w_t) in LDS.
// Phase 2: composite_rgb[c] = sum_t v_t * colors[t][c] -- pure streaming
// FMA pass over colors (402 MB), no serial dependency.
__global__ __launch_bounds__(256) void k_march(
    const float* __restrict__ colors,
    const float* __restrict__ dens,
    const float* __restrict__ deps,
    const unsigned int* __restrict__ ws,
    float* __restrict__ out) {
  const int tid      = threadIdx.x;
  const int lane     = tid & 7;        // float4 chunk / segment-group within ray
  const int rayInBlk = tid >> 3;       // 0..31
  const int ray      = blockIdx.x * 32 + rayInBlk;

  __shared__ __align__(16) float vlds[32 * VSTR];  // per-ray color coefficients v_t
  __shared__ float wlds[32 * WSTR];                // per-ray weights (writeback staging)

  // ---------------- phase 1: transmittance scan ----------------
  {
    // lane l owns samples 6l..6l+5 and segments 6l..6l+5 (lane 7: last seg masked)
    const float* dp = dens + (size_t)ray * Sn + lane * 6;
    const float* zp = deps + (size_t)ray * Sn + lane * 6;
    float d[6], z[6];
    float2 u;
    u = *(const float2*)(dp + 0); d[0] = u.x; d[1] = u.y;
    u = *(const float2*)(dp + 2); d[2] = u.x; d[3] = u.y;
    u = *(const float2*)(dp + 4); d[4] = u.x; d[5] = u.y;
    u = *(const float2*)(zp + 0); z[0] = u.x; z[1] = u.y;
    u = *(const float2*)(zp + 2); z[2] = u.x; z[3] = u.y;
    u = *(const float2*)(zp + 4); z[4] = u.x; z[5] = u.y;

    // sample 6l+6 = next lane's first sample
    float dnx = __shfl_down(d[0], 1, 8);
    float znx = __shfl_down(z[0], 1, 8);
    const bool lastLane = (lane == 7);

    float a[6], q[6], zm[6];
#pragma unroll
    for (int j = 0; j < 6; ++j) {
      float dj1 = (j < 5) ? d[j + 1] : dnx;
      float zj1 = (j < 5) ? z[j + 1] : znx;
      float delta = zj1 - z[j];
      if (j == 5 && lastLane) delta = 0.0f;  // segment 47 doesn't exist -> inert (a=0,q=1)
      float x  = 0.5f * (d[j] + dj1) - 1.0f;
      float sp = fmaxf(x, 0.0f) + log1pf(expf(-fabsf(x)));  // jax softplus
      float e  = expf(-sp * delta);
      a[j]  = 1.0f - e;          // alpha
      q[j]  = e + 1e-10f;        // (1 - alpha) + 1e-10
      zm[j] = 0.5f * (z[j] + zj1);
    }

    // per-lane product of q, then inclusive Hillis-Steele scan over the 8-lane group
    float P  = ((q[0] * q[1]) * (q[2] * q[3])) * (q[4] * q[5]);
    float ip = P;
#pragma unroll
    for (int o = 1; o < 8; o <<= 1) {
      float other = __shfl_up(ip, o, 8);
      if (lane >= o) ip *= other;
    }
    float T = __shfl_up(ip, 1, 8);   // exclusive: product of all q before segment 6l
    if (lane == 0) T = 1.0f;

    float w[6];
    float wsum = 0.f, dsum = 0.f;
#pragma unroll
    for (int j = 0; j < 6; ++j) {
      w[j] = a[j] * T;               // lane7 j=5: a=0 -> w=0 (w_47 == 0)
      T *= q[j];
      wsum += w[j];
      dsum += w[j] * zm[j];
    }

    // v_t = 0.5*(w_{t-1} + w_t); lane needs previous lane's last weight
    float wprev = __shfl_up(w[5], 1, 8);
    if (lane == 0) wprev = 0.0f;     // w_{-1} = 0

    float* vr = vlds + rayInBlk * VSTR + lane * 6;
    float* wr = wlds + rayInBlk * WSTR + lane * 6;
    vr[0] = 0.5f * (wprev + w[0]);
#pragma unroll
    for (int j = 1; j < 6; ++j) vr[j] = 0.5f * (w[j - 1] + w[j]);  // lane7 j=5 -> v_47 = 0.5*w_46
#pragma unroll
    for (int j = 0; j < 6; ++j) wr[j] = w[j];  // lane7 j=5 lands in slot 47 (<WSTR), never read back

    // 8-lane reductions for depth composite
#pragma unroll
    for (int o = 1; o < 8; o <<= 1) {
      wsum += __shfl_xor(wsum, o, 8);
      dsum += __shfl_xor(dsum, o, 8);
    }
    if (lane == 0) {
      float cd = dsum / wsum;
      if (cd != cd) cd = INFINITY;   // nan_to_num(nan=inf)
      float dmin = __uint_as_float(ws[0]);
      float dmax = __uint_as_float(ws[1]);
      cd = fminf(fmaxf(cd, dmin), dmax);
      out[OUT_DEPTH_OFF + ray] = cd;
    }
  }

  // ---------------- phase 2: stream colors (pure FMA dot-product) ----------------
  // v rows are written and read by the SAME wave (8 rays == 64 lanes) -> no barrier.
  {
    const float4* __restrict__ cp =
        (const float4*)(colors + (size_t)ray * (Sn * Cn)) + lane;
    const float* vrow = vlds + rayInBlk * VSTR;
    float ax = 0.f, ay = 0.f, az = 0.f, aw = 0.f;

#define FMA4(vs, g) do { ax = fmaf(vs, g.x, ax); ay = fmaf(vs, g.y, ay); \
                         az = fmaf(vs, g.z, az); aw = fmaf(vs, g.w, aw); } while (0)

    for (int t0 = 0; t0 < Sn; t0 += 8) {
      float4 va = *(const float4*)(vrow + t0);      // LDS broadcast within ray
      float4 vb = *(const float4*)(vrow + t0 + 4);
      float4 g0 = cp[(t0 + 0) * 8];
      float4 g1 = cp[(t0 + 1) * 8];
      float4 g2 = cp[(t0 + 2) * 8];
      float4 g3 = cp[(t0 + 3) * 8];
      float4 g4 = cp[(t0 + 4) * 8];
      float4 g5 = cp[(t0 + 5) * 8];
      float4 g6 = cp[(t0 + 6) * 8];
      float4 g7 = cp[(t0 + 7) * 8];
      FMA4(va.x, g0); FMA4(va.y, g1); FMA4(va.z, g2); FMA4(va.w, g3);
      FMA4(vb.x, g4); FMA4(vb.y, g5); FMA4(vb.z, g6); FMA4(vb.w, g7);
    }
#undef FMA4

    // composite_rgb = rgb*2-1, coalesced float4 store
    float4 o;
    o.x = ax * 2.f - 1.f; o.y = ay * 2.f - 1.f;
    o.z = az * 2.f - 1.f; o.w = aw * 2.f - 1.f;
    ((float4*)(out + (size_t)ray * Cn))[lane] = o;
  }

  // ---------------- coalesced weights writeback ----------------
  __syncthreads();
  float* wout = out + OUT_W_OFF + (size_t)blockIdx.x * (32 * SM1);
  for (int i = tid; i < 32 * SM1; i += 256) {
    int r = i / SM1;
    int s = i - r * SM1;
    wout[i] = wlds[r * WSTR + s];
  }
}

extern "C" void kernel_launch(void* const* d_in, const int* in_sizes, int n_in,
                              void* d_out, int out_size, void* d_ws, size_t ws_size,
                              hipStream_t stream) {
  const float* colors = (const float*)d_in[0];
  const float* dens   = (const float*)d_in[1];
  const float* deps   = (const float*)d_in[2];
  float* out          = (float*)d_out;
  unsigned int* ws    = (unsigned int*)d_ws;

  k_init<<<1, 1, 0, stream>>>(ws);
  k_minmax<<<NRAY / 256, 256, 0, stream>>>(deps, ws);
  k_march<<<NRAY / 32, 256, 0, stream>>>(colors, dens, deps, ws, out);
}

// Round 3
// 549.106 us; speedup vs baseline: 1.0410x; 1.0006x over previous
//
#include <hip/hip_runtime.h>
#include <math.h>

// Problem constants (match reference)
constexpr int Bn = 4, Rn = 16384, Sn = 48, Cn = 32;
constexpr int NRAY = Bn * Rn;                 // 65536 rays
constexpr int SM1  = Sn - 1;                  // 47 segments
constexpr int OUT_DEPTH_OFF = NRAY * Cn;      // rgb block size
constexpr int OUT_W_OFF     = OUT_DEPTH_OFF + NRAY;

// ---- pass 0: init global min/max cells in workspace --------------------
__global__ void k_init(unsigned int* ws) {
  ws[0] = 0xFFFFFFFFu;  // running min (uint order == float order for positives)
  ws[1] = 0u;           // running max
}

// ---- pass 1: global min/max of depths (sorted per ray -> first/last) ---
__global__ void k_minmax(const float* __restrict__ depths, unsigned int* ws) {
  int ray = blockIdx.x * blockDim.x + threadIdx.x;
  float lo = depths[(size_t)ray * Sn];
  float hi = depths[(size_t)ray * Sn + (Sn - 1)];
#pragma unroll
  for (int off = 32; off > 0; off >>= 1) {
    lo = fminf(lo, __shfl_down(lo, off, 64));
    hi = fmaxf(hi, __shfl_down(hi, off, 64));
  }
  __shared__ float slo[4], shi[4];
  int wv = threadIdx.x >> 6;
  if ((threadIdx.x & 63) == 0) { slo[wv] = lo; shi[wv] = hi; }
  __syncthreads();
  if (threadIdx.x == 0) {
    for (int i = 1; i < 4; ++i) { lo = fminf(lo, slo[i]); hi = fmaxf(hi, shi[i]); }
    atomicMin(ws + 0, __float_as_uint(lo));
    atomicMax(ws + 1, __float_as_uint(hi));
  }
}

// ---- pass 2: one WAVE per ray --------------------------------------------
// Phase 2 loads are 1KB-contiguous per wave instruction (the 6.3 TB/s copy
// pattern). Phase 1 is a 64-lane parallel transmittance scan. Barrier-free.
__global__ __launch_bounds__(256) void k_march(
    const float* __restrict__ colors,
    const float* __restrict__ dens,
    const float* __restrict__ deps,
    const unsigned int* __restrict__ ws,
    float* __restrict__ out) {
  const int tid  = threadIdx.x;
  const int lane = tid & 63;
  const int wv   = tid >> 6;                    // wave in block: 0..3
  const int ray  = blockIdx.x * 4 + wv;

  __shared__ float vlds[4][48];                 // per-ray color coefficients v_t

  // ---- issue color loads FIRST (6 x 1KB contiguous per wave); latency
  // hides under the phase-1 scan math (T14 issue-early) ----
  const float4* __restrict__ cp = (const float4*)(colors + (size_t)ray * (Sn * Cn));
  float4 f0 = cp[0 * 64 + lane];
  float4 f1 = cp[1 * 64 + lane];
  float4 f2 = cp[2 * 64 + lane];
  float4 f3 = cp[3 * 64 + lane];
  float4 f4 = cp[4 * 64 + lane];
  float4 f5 = cp[5 * 64 + lane];

  // ---------------- phase 1: 64-lane transmittance scan ----------------
  // lane l owns sample l (l<48) and segment l (l<47)
  const float* zp = deps + (size_t)ray * Sn;
  const float* dp = dens + (size_t)ray * Sn;
  float z = (lane < Sn) ? zp[lane] : 0.0f;
  float d = (lane < Sn) ? dp[lane] : 0.0f;
  float z1 = __shfl_down(z, 1, 64);             // sample l+1
  float d1 = __shfl_down(d, 1, 64);
  const bool seg = (lane < SM1);

  float delta = seg ? (z1 - z) : 0.0f;          // inert lanes: delta=0 -> e=1
  float x  = 0.5f * (d + d1) - 1.0f;
  float sp = fmaxf(x, 0.0f) + log1pf(expf(-fabsf(x)));  // jax softplus
  float e  = expf(-sp * delta);
  float a  = seg ? (1.0f - e) : 0.0f;           // alpha (w=0 on inert lanes)
  float q  = e + 1e-10f;                        // (1-alpha)+1e-10
  float zm = 0.5f * (z + z1);

  // inclusive product scan over 64 lanes -> exclusive transmittance T
  float ip = q;
#pragma unroll
  for (int o = 1; o < 64; o <<= 1) {
    float other = __shfl_up(ip, o, 64);
    if (lane >= o) ip *= other;
  }
  float T = __shfl_up(ip, 1, 64);
  if (lane == 0) T = 1.0f;
  float w = a * T;                              // weight for segment l (0 for l>=47)

  // wsum / dsum reductions (lanes with w=0 contribute nothing)
  float wsum = w, dsum = w * zm;
#pragma unroll
  for (int o = 1; o < 64; o <<= 1) {
    wsum += __shfl_xor(wsum, o, 64);
    dsum += __shfl_xor(dsum, o, 64);
  }

  // v_t = 0.5*(w_{t-1} + w_t), t=0..47 (w_{-1} = w_47 = 0)
  float wp = __shfl_up(w, 1, 64);
  if (lane == 0) wp = 0.0f;
  float v = 0.5f * (wp + w);
  if (lane < Sn) vlds[wv][lane] = v;

  // weights writeback: 47 contiguous floats per ray
  if (lane < SM1) out[OUT_W_OFF + (size_t)ray * SM1 + lane] = w;

  // composite depth
  if (lane == 0) {
    float cd = dsum / wsum;
    if (cd != cd) cd = INFINITY;                // nan_to_num(nan=inf)
    float dmin = __uint_as_float(ws[0]);
    float dmax = __uint_as_float(ws[1]);
    cd = fminf(fmaxf(cd, dmin), dmax);
    out[OUT_DEPTH_OFF + ray] = cd;
  }

  // ---------------- phase 2: dot-product on the prefetched colors --------
  // float4 index i = g*64+lane -> t = 8g + (lane>>3), c4 = lane&7
  const int tb = lane >> 3;
  const float* vr = vlds[wv];
  float v0 = vr[0 * 8 + tb];
  float v1 = vr[1 * 8 + tb];
  float v2 = vr[2 * 8 + tb];
  float v3 = vr[3 * 8 + tb];
  float v4 = vr[4 * 8 + tb];
  float v5 = vr[5 * 8 + tb];

  float ax, ay, az, aw;
  ax = f0.x * v0; ay = f0.y * v0; az = f0.z * v0; aw = f0.w * v0;
  ax = fmaf(f1.x, v1, ax); ay = fmaf(f1.y, v1, ay); az = fmaf(f1.z, v1, az); aw = fmaf(f1.w, v1, aw);
  ax = fmaf(f2.x, v2, ax); ay = fmaf(f2.y, v2, ay); az = fmaf(f2.z, v2, az); aw = fmaf(f2.w, v2, aw);
  ax = fmaf(f3.x, v3, ax); ay = fmaf(f3.y, v3, ay); az = fmaf(f3.z, v3, az); aw = fmaf(f3.w, v3, aw);
  ax = fmaf(f4.x, v4, ax); ay = fmaf(f4.y, v4, ay); az = fmaf(f4.z, v4, az); aw = fmaf(f4.w, v4, aw);
  ax = fmaf(f5.x, v5, ax); ay = fmaf(f5.y, v5, ay); az = fmaf(f5.z, v5, az); aw = fmaf(f5.w, v5, aw);

  // reduce across the 8 t-groups (lanes sharing c4 = lane&7)
#pragma unroll
  for (int o = 8; o < 64; o <<= 1) {
    ax += __shfl_xor(ax, o, 64);
    ay += __shfl_xor(ay, o, 64);
    az += __shfl_xor(az, o, 64);
    aw += __shfl_xor(aw, o, 64);
  }

  if (lane < 8) {
    float4 o4;
    o4.x = ax * 2.f - 1.f; o4.y = ay * 2.f - 1.f;
    o4.z = az * 2.f - 1.f; o4.w = aw * 2.f - 1.f;
    ((float4*)(out + (size_t)ray * Cn))[lane] = o4;   // 128B contiguous per ray
  }
}

extern "C" void kernel_launch(void* const* d_in, const int* in_sizes, int n_in,
                              void* d_out, int out_size, void* d_ws, size_t ws_size,
                              hipStream_t stream) {
  const float* colors = (const float*)d_in[0];
  const float* dens   = (const float*)d_in[1];
  const float* deps   = (const float*)d_in[2];
  float* out          = (float*)d_out;
  unsigned int* ws    = (unsigned int*)d_ws;

  k_init<<<1, 1, 0, stream>>>(ws);
  k_minmax<<<NRAY / 256, 256, 0, stream>>>(deps, ws);
  k_march<<<NRAY / 4, 256, 0, stream>>>(colors, dens, deps, ws, out);
}